// Round 1
// baseline (843.393 us; speedup 1.0000x reference)
//
#include <hip/hip_runtime.h>
#include <math.h>

#define B_    32
#define CIN_  256
#define HW_   784
#define H_    28
#define W_    28
#define COUT_ 256
#define KEXP_ 4
#define HID_  64

// ---------------- Kernel 1: global average pool (one wave per (b,c)) ----------------
__global__ __launch_bounds__(256) void pool_kernel(const float* __restrict__ x,
                                                   float* __restrict__ pooled) {
    int w = blockIdx.x * 4 + (threadIdx.x >> 6);   // 0 .. B*CIN-1
    int lane = threadIdx.x & 63;
    const float* p = x + (size_t)w * HW_;
    float s = 0.f;
    for (int i = lane; i < HW_; i += 64) s += p[i];
    for (int off = 32; off; off >>= 1) s += __shfl_down(s, off);
    if (lane == 0) pooled[w] = s * (1.0f / HW_);
}

// ---------------- Kernel 2: SE MLP + softmax over K ----------------
__global__ __launch_bounds__(256) void se_kernel(const float* __restrict__ pooled,
                                                 const float* __restrict__ fc1_w,
                                                 const float* __restrict__ fc2_w,
                                                 const float* __restrict__ fc2_b,
                                                 float* __restrict__ prob) {
    __shared__ float pl[CIN_];
    __shared__ float h[HID_];
    int b = blockIdx.x, t = threadIdx.x;
    pl[t] = pooled[b * CIN_ + t];
    __syncthreads();
    if (t < HID_) {
        float s = 0.f;
        const float* wr = fc1_w + t * CIN_;
        for (int c = 0; c < CIN_; ++c) s += pl[c] * wr[c];
        h[t] = fmaxf(s, 0.f);
    }
    __syncthreads();
    int o = t;
    float yk[KEXP_];
    for (int k = 0; k < KEXP_; ++k) {
        int r = k * COUT_ + o;
        float s = fc2_b[r];
        const float* wr = fc2_w + r * HID_;
        for (int j = 0; j < HID_; ++j) s += h[j] * wr[j];
        yk[k] = s * 0.125f;   // / sqrt(HIDDEN=64)
    }
    float m = yk[0];
    for (int k = 1; k < KEXP_; ++k) m = fmaxf(m, yk[k]);
    float e[KEXP_], sum = 0.f;
    for (int k = 0; k < KEXP_; ++k) { e[k] = expf(yk[k] - m); sum += e[k]; }
    float inv = 1.0f / sum;
    for (int k = 0; k < KEXP_; ++k)
        prob[b * (KEXP_ * COUT_) + k * COUT_ + o] = e[k] * inv;
}

// ---------------- Kernel 3: fused weight-aggregation + direct conv ----------------
// grid = B * (COUT/8) blocks; block computes out[b, o0:o0+8, :, :]
__global__ __launch_bounds__(256) void conv_kernel(const float* __restrict__ x,
                                                   const float* __restrict__ weight,
                                                   const float* __restrict__ prob,
                                                   float* __restrict__ out) {
    __shared__ float xs[30 * 30];          // haloed input plane
    __shared__ float wagg[8][32][12];      // aggregated weights, padded to 12 for 16B align
    __shared__ float pl[KEXP_][8];

    int b  = blockIdx.x >> 5;
    int o0 = (blockIdx.x & 31) * 8;
    int t  = threadIdx.x;

    if (t < 32) {
        int k = t >> 3, oc = t & 7;
        pl[k][oc] = prob[b * (KEXP_ * COUT_) + k * COUT_ + o0 + oc];
    }

    // per-thread pixels: p0, p0+256, p0+512, p0+768 (mask >= 784)
    int p0 = t;
    int pr[4], pc[4];
    bool pv[4];
    #pragma unroll
    for (int j = 0; j < 4; ++j) {
        int p = p0 + j * 256;
        pv[j] = p < HW_;
        pr[j] = p / W_;
        pc[j] = p % W_;
    }

    float acc[8][4];
    #pragma unroll
    for (int oc = 0; oc < 8; ++oc)
        #pragma unroll
        for (int j = 0; j < 4; ++j) acc[oc][j] = 0.f;

    int aoc = t >> 5, aii = t & 31;

    for (int ic0 = 0; ic0 < CIN_; ic0 += 32) {
        __syncthreads();   // prev chunk's compute done (and pl ready on first iter)
        // aggregate expert weights for channels [ic0, ic0+32)
        {
            float w9[9];
            #pragma unroll
            for (int j = 0; j < 9; ++j) w9[j] = 0.f;
            int i = ic0 + aii;
            #pragma unroll
            for (int k = 0; k < KEXP_; ++k) {
                float pk = pl[k][aoc];
                const float* wp = weight + ((size_t)(k * COUT_ + o0 + aoc) * CIN_ + i) * 9;
                #pragma unroll
                for (int j = 0; j < 9; ++j) w9[j] += pk * wp[j];
            }
            #pragma unroll
            for (int j = 0; j < 9; ++j) wagg[aoc][aii][j] = w9[j];
        }

        for (int ii = 0; ii < 32; ++ii) {
            int i = ic0 + ii;
            __syncthreads();   // prev xs reads done; wagg visible on ii==0
            const float* xp = x + (size_t)(b * CIN_ + i) * HW_;
            for (int e = t; e < 900; e += 256) {
                int ry = e / 30, cx = e - ry * 30;
                int gy = ry - 1, gx = cx - 1;
                float v = 0.f;
                if ((unsigned)gy < 28u && (unsigned)gx < 28u) v = xp[gy * W_ + gx];
                xs[e] = v;
            }
            __syncthreads();

            float xv[4][9];
            #pragma unroll
            for (int j = 0; j < 4; ++j) {
                if (pv[j]) {
                    const float* xr = &xs[pr[j] * 30 + pc[j]];
                    xv[j][0] = xr[0];  xv[j][1] = xr[1];  xv[j][2] = xr[2];
                    xv[j][3] = xr[30]; xv[j][4] = xr[31]; xv[j][5] = xr[32];
                    xv[j][6] = xr[60]; xv[j][7] = xr[61]; xv[j][8] = xr[62];
                } else {
                    #pragma unroll
                    for (int q = 0; q < 9; ++q) xv[j][q] = 0.f;
                }
            }
            #pragma unroll
            for (int oc = 0; oc < 8; ++oc) {
                float4 wa = *(const float4*)&wagg[oc][ii][0];
                float4 wb = *(const float4*)&wagg[oc][ii][4];
                float  wc = wagg[oc][ii][8];
                #pragma unroll
                for (int j = 0; j < 4; ++j) {
                    acc[oc][j] += xv[j][0] * wa.x + xv[j][1] * wa.y + xv[j][2] * wa.z
                                + xv[j][3] * wa.w + xv[j][4] * wb.x + xv[j][5] * wb.y
                                + xv[j][6] * wb.z + xv[j][7] * wb.w + xv[j][8] * wc;
                }
            }
        }
    }

    #pragma unroll
    for (int oc = 0; oc < 8; ++oc) {
        float* op = out + (size_t)(b * COUT_ + o0 + oc) * HW_ + p0;
        #pragma unroll
        for (int j = 0; j < 4; ++j)
            if (pv[j]) op[j * 256] = acc[oc][j];
    }
}

extern "C" void kernel_launch(void* const* d_in, const int* in_sizes, int n_in,
                              void* d_out, int out_size, void* d_ws, size_t ws_size,
                              hipStream_t stream) {
    const float* x     = (const float*)d_in[0];
    const float* fc1_w = (const float*)d_in[1];
    const float* fc2_w = (const float*)d_in[2];
    const float* fc2_b = (const float*)d_in[3];
    const float* weight= (const float*)d_in[4];
    float* out = (float*)d_out;

    float* pooled = (float*)d_ws;              // B*CIN = 8192 floats
    float* prob   = pooled + B_ * CIN_;        // B*K*COUT = 32768 floats

    pool_kernel<<<(B_ * CIN_) / 4, 256, 0, stream>>>(x, pooled);
    se_kernel<<<B_, 256, 0, stream>>>(pooled, fc1_w, fc2_w, fc2_b, prob);
    conv_kernel<<<B_ * (COUT_ / 8), 256, 0, stream>>>(x, weight, prob, out);
}

// Round 2
// 169.460 us; speedup vs baseline: 4.9770x; 4.9770x over previous
//
#include <hip/hip_runtime.h>
#include <math.h>

#define B_    32
#define CIN_  256
#define HW_   784
#define H_    28
#define W_    28
#define COUT_ 256
#define KEXP_ 4
#define HID_  64

typedef short short8 __attribute__((ext_vector_type(8)));
typedef float floatx16 __attribute__((ext_vector_type(16)));

__device__ __forceinline__ unsigned short f2bf(float f) {
    union { float f; unsigned int u; } v; v.f = f;
    unsigned int r = (v.u + 0x7FFFu + ((v.u >> 16) & 1u)) >> 16;
    return (unsigned short)r;
}

// ---------------- Kernel 1: global average pool (one wave per (b,c)) ----------------
__global__ __launch_bounds__(256) void pool_kernel(const float* __restrict__ x,
                                                   float* __restrict__ pooled) {
    int w = blockIdx.x * 4 + (threadIdx.x >> 6);
    int lane = threadIdx.x & 63;
    const float* p = x + (size_t)w * HW_;
    float s = 0.f;
    for (int i = lane; i < HW_; i += 64) s += p[i];
    for (int off = 32; off; off >>= 1) s += __shfl_down(s, off);
    if (lane == 0) pooled[w] = s * (1.0f / HW_);
}

// ---------------- Kernel 2: SE MLP + softmax over K ----------------
__global__ __launch_bounds__(256) void se_kernel(const float* __restrict__ pooled,
                                                 const float* __restrict__ fc1_w,
                                                 const float* __restrict__ fc2_w,
                                                 const float* __restrict__ fc2_b,
                                                 float* __restrict__ prob) {
    __shared__ float pl[CIN_];
    __shared__ float h[HID_];
    int b = blockIdx.x, t = threadIdx.x;
    pl[t] = pooled[b * CIN_ + t];
    __syncthreads();
    if (t < HID_) {
        float s = 0.f;
        const float* wr = fc1_w + t * CIN_;
        for (int c = 0; c < CIN_; ++c) s += pl[c] * wr[c];
        h[t] = fmaxf(s, 0.f);
    }
    __syncthreads();
    int o = t;
    float yk[KEXP_];
    for (int k = 0; k < KEXP_; ++k) {
        int r = k * COUT_ + o;
        float s = fc2_b[r];
        const float* wr = fc2_w + r * HID_;
        for (int j = 0; j < HID_; ++j) s += h[j] * wr[j];
        yk[k] = s * 0.125f;
    }
    float m = yk[0];
    for (int k = 1; k < KEXP_; ++k) m = fmaxf(m, yk[k]);
    float e[KEXP_], sum = 0.f;
    for (int k = 0; k < KEXP_; ++k) { e[k] = expf(yk[k] - m); sum += e[k]; }
    float inv = 1.0f / sum;
    for (int k = 0; k < KEXP_; ++k)
        prob[b * (KEXP_ * COUT_) + k * COUT_ + o] = e[k] * inv;
}

// ---------------- Kernel 3: transpose x [b][ic][px] f32 -> x_t [b][px][ic] bf16 ----------------
__global__ __launch_bounds__(256) void xpose_kernel(const float* __restrict__ x,
                                                    unsigned short* __restrict__ x_t) {
    __shared__ float tile[32][33];
    int bid = blockIdx.x;              // 32 * 8 * 25
    int b   = bid / 200;
    int rem = bid - b * 200;
    int ic0 = (rem / 25) * 32;
    int px0 = (rem % 25) * 32;
    int t = threadIdx.x;
    int c = t & 31, rr = t >> 5;
    #pragma unroll
    for (int r = 0; r < 4; ++r) {
        int icr = rr + r * 8;
        int px = px0 + c;
        float v = (px < HW_) ? x[((size_t)(b * CIN_ + ic0 + icr)) * HW_ + px] : 0.f;
        tile[icr][c] = v;
    }
    __syncthreads();
    #pragma unroll
    for (int r = 0; r < 4; ++r) {
        int pxr = rr + r * 8;
        int px = px0 + pxr;
        if (px < HW_)
            x_t[((size_t)b * HW_ + px) * CIN_ + ic0 + c] = f2bf(tile[c][pxr]);
    }
}

// ---------------- Kernel 4: aggregate expert weights -> agg[b][rs][oc][ic] bf16 ----------------
// one block per oc
__global__ __launch_bounds__(256) void agg_kernel(const float* __restrict__ weight,
                                                  const float* __restrict__ prob,
                                                  unsigned short* __restrict__ agg) {
    __shared__ float ws_w[KEXP_ * CIN_ * 9];   // [k][ic*9+rs], 36 KB
    __shared__ float pb[KEXP_][B_];
    int oc = blockIdx.x, t = threadIdx.x;
    for (int e = t; e < KEXP_ * CIN_ * 9; e += 256) {
        int k = e / (CIN_ * 9);
        int r = e - k * (CIN_ * 9);
        ws_w[e] = weight[((size_t)(k * COUT_ + oc)) * (CIN_ * 9) + r];
    }
    if (t < KEXP_ * B_) {
        int k = t >> 5, b = t & 31;
        pb[k][b] = prob[b * (KEXP_ * COUT_) + k * COUT_ + oc];
    }
    __syncthreads();
    int ic = t;
    for (int rs = 0; rs < 9; ++rs) {
        float w0 = ws_w[0 * CIN_ * 9 + ic * 9 + rs];
        float w1 = ws_w[1 * CIN_ * 9 + ic * 9 + rs];
        float w2 = ws_w[2 * CIN_ * 9 + ic * 9 + rs];
        float w3 = ws_w[3 * CIN_ * 9 + ic * 9 + rs];
        for (int b = 0; b < B_; ++b) {
            float s = pb[0][b] * w0 + pb[1][b] * w1 + pb[2][b] * w2 + pb[3][b] * w3;
            agg[(((size_t)b * 9 + rs) * COUT_ + oc) * CIN_ + ic] = f2bf(s);
        }
    }
}

// ---------------- Kernel 5: MFMA implicit-GEMM conv ----------------
// grid = 7 rowblk * 64 (b*2+ochalf); block 256 threads = 4 waves
// block computes out[b, oc0:oc0+128, py0:py0+4, :]
__global__ __launch_bounds__(256, 3) void conv_mfma_kernel(const unsigned short* __restrict__ x_t,
                                                           const unsigned short* __restrict__ agg,
                                                           float* __restrict__ out) {
    __shared__ __align__(16) short Xs[6 * 35 * 72];   // [row][col][ic(64 pad 72)] 30240 B
    __shared__ __align__(16) short As[128 * 72];      // [oc'][ic(64 pad 72)]      18432 B

    int gid = blockIdx.x;
    int rowblk = gid >> 6;
    int pair = gid & 63;
    int b = pair >> 1;
    int oc0 = (pair & 1) * 128;
    int py0 = rowblk * 4;

    int t = threadIdx.x;
    int lane = t & 63, w = t >> 6;
    int ml = lane & 31, kh = lane >> 5;

    floatx16 acc[4];
    #pragma unroll
    for (int j = 0; j < 4; ++j)
        #pragma unroll
        for (int r = 0; r < 16; ++r) acc[j][r] = 0.f;

    const unsigned short* xtb = x_t + (size_t)b * HW_ * CIN_;

    for (int ic0 = 0; ic0 < CIN_; ic0 += 64) {
        __syncthreads();   // all readers of previous Xs/As done
        // ---- stage Xs: rows py0-1..py0+4, cols -1..33, 64 ic ----
        #pragma unroll
        for (int i = 0; i < 7; ++i) {
            int l = t + i * 256;
            if (l < 6 * 35 * 8) {
                int pos = l >> 3, g = l & 7;
                int row = pos / 35, col = pos - row * 35;
                int gy = py0 - 1 + row, gx = col - 1;
                short8 v = (short8)0;
                if ((unsigned)gy < 28u && (unsigned)gx < 28u)
                    v = *(const short8*)(xtb + ((size_t)(gy * W_ + gx)) * CIN_ + ic0 + g * 8);
                *(short8*)&Xs[pos * 72 + g * 8] = v;
            }
        }
        for (int rs = 0; rs < 9; ++rs) {
            int dy = rs / 3, dx = rs - dy * 3;
            if (rs) __syncthreads();   // prev-tap MFMAs done before As overwrite
            // ---- stage As: 128 oc x 64 ic ----
            const unsigned short* ag = agg + ((((size_t)b * 9 + rs) * COUT_ + oc0)) * CIN_ + ic0;
            #pragma unroll
            for (int i = 0; i < 4; ++i) {
                int l = t + i * 256;
                int row = l >> 3, g = l & 7;
                *(short8*)&As[row * 72 + g * 8] = *(const short8*)(ag + (size_t)row * CIN_ + g * 8);
            }
            __syncthreads();
            // ---- MFMA: 4 ksteps x 4 n-tiles ----
            #pragma unroll
            for (int kk = 0; kk < 4; ++kk) {
                short8 a = *(const short8*)&As[(w * 32 + ml) * 72 + kk * 16 + kh * 8];
                #pragma unroll
                for (int j = 0; j < 4; ++j) {
                    short8 bf = *(const short8*)&Xs[((j + dy) * 35 + (ml + dx)) * 72 + kk * 16 + kh * 8];
                    acc[j] = __builtin_amdgcn_mfma_f32_32x32x16_bf16(a, bf, acc[j], 0, 0, 0);
                }
            }
        }
    }

    // ---- epilogue: D layout col=lane&31, row=(reg&3)+8*(reg>>2)+4*(lane>>5) ----
    int col = ml;
    if (col < W_) {
        #pragma unroll
        for (int j = 0; j < 4; ++j) {
            int y = py0 + j;
            #pragma unroll
            for (int r = 0; r < 16; ++r) {
                int ocg = oc0 + w * 32 + (r & 3) + 8 * (r >> 2) + 4 * kh;
                out[((size_t)(b * COUT_ + ocg)) * HW_ + y * W_ + col] = acc[j][r];
            }
        }
    }
}

// ---------------- Fallback fp32 direct conv (round-1, used if ws too small) ----------------
__global__ __launch_bounds__(256) void conv_kernel(const float* __restrict__ x,
                                                   const float* __restrict__ weight,
                                                   const float* __restrict__ prob,
                                                   float* __restrict__ out) {
    __shared__ float xs[30 * 30];
    __shared__ float wagg[8][32][12];
    __shared__ float pl[KEXP_][8];

    int b  = blockIdx.x >> 5;
    int o0 = (blockIdx.x & 31) * 8;
    int t  = threadIdx.x;

    if (t < 32) {
        int k = t >> 3, oc = t & 7;
        pl[k][oc] = prob[b * (KEXP_ * COUT_) + k * COUT_ + o0 + oc];
    }
    int p0 = t;
    int pr[4], pc[4];
    bool pv[4];
    #pragma unroll
    for (int j = 0; j < 4; ++j) {
        int p = p0 + j * 256;
        pv[j] = p < HW_;
        pr[j] = p / W_;
        pc[j] = p % W_;
    }
    float acc[8][4];
    #pragma unroll
    for (int oc = 0; oc < 8; ++oc)
        #pragma unroll
        for (int j = 0; j < 4; ++j) acc[oc][j] = 0.f;

    int aoc = t >> 5, aii = t & 31;

    for (int ic0 = 0; ic0 < CIN_; ic0 += 32) {
        __syncthreads();
        {
            float w9[9];
            #pragma unroll
            for (int j = 0; j < 9; ++j) w9[j] = 0.f;
            int i = ic0 + aii;
            #pragma unroll
            for (int k = 0; k < KEXP_; ++k) {
                float pk = pl[k][aoc];
                const float* wp = weight + ((size_t)(k * COUT_ + o0 + aoc) * CIN_ + i) * 9;
                #pragma unroll
                for (int j = 0; j < 9; ++j) w9[j] += pk * wp[j];
            }
            #pragma unroll
            for (int j = 0; j < 9; ++j) wagg[aoc][aii][j] = w9[j];
        }
        for (int ii = 0; ii < 32; ++ii) {
            int i = ic0 + ii;
            __syncthreads();
            const float* xp = x + (size_t)(b * CIN_ + i) * HW_;
            for (int e = t; e < 900; e += 256) {
                int ry = e / 30, cx = e - ry * 30;
                int gy = ry - 1, gx = cx - 1;
                float v = 0.f;
                if ((unsigned)gy < 28u && (unsigned)gx < 28u) v = xp[gy * W_ + gx];
                xs[e] = v;
            }
            __syncthreads();
            float xv[4][9];
            #pragma unroll
            for (int j = 0; j < 4; ++j) {
                if (pv[j]) {
                    const float* xr = &xs[pr[j] * 30 + pc[j]];
                    xv[j][0] = xr[0];  xv[j][1] = xr[1];  xv[j][2] = xr[2];
                    xv[j][3] = xr[30]; xv[j][4] = xr[31]; xv[j][5] = xr[32];
                    xv[j][6] = xr[60]; xv[j][7] = xr[61]; xv[j][8] = xr[62];
                } else {
                    #pragma unroll
                    for (int q = 0; q < 9; ++q) xv[j][q] = 0.f;
                }
            }
            #pragma unroll
            for (int oc = 0; oc < 8; ++oc) {
                float4 wa = *(const float4*)&wagg[oc][ii][0];
                float4 wb = *(const float4*)&wagg[oc][ii][4];
                float  wc = wagg[oc][ii][8];
                #pragma unroll
                for (int j = 0; j < 4; ++j) {
                    acc[oc][j] += xv[j][0] * wa.x + xv[j][1] * wa.y + xv[j][2] * wa.z
                                + xv[j][3] * wa.w + xv[j][4] * wb.x + xv[j][5] * wb.y
                                + xv[j][6] * wb.z + xv[j][7] * wb.w + xv[j][8] * wc;
                }
            }
        }
    }
    #pragma unroll
    for (int oc = 0; oc < 8; ++oc) {
        float* op = out + (size_t)(b * COUT_ + o0 + oc) * HW_ + p0;
        #pragma unroll
        for (int j = 0; j < 4; ++j)
            if (pv[j]) op[j * 256] = acc[oc][j];
    }
}

extern "C" void kernel_launch(void* const* d_in, const int* in_sizes, int n_in,
                              void* d_out, int out_size, void* d_ws, size_t ws_size,
                              hipStream_t stream) {
    const float* x     = (const float*)d_in[0];
    const float* fc1_w = (const float*)d_in[1];
    const float* fc2_w = (const float*)d_in[2];
    const float* fc2_b = (const float*)d_in[3];
    const float* weight= (const float*)d_in[4];
    float* out = (float*)d_out;

    char* ws = (char*)d_ws;
    float* pooled = (float*)(ws);                    //  32 KB
    float* prob   = (float*)(ws + 32768);            // 128 KB
    unsigned short* x_t = (unsigned short*)(ws + 163840);        // 12.85 MB
    unsigned short* agg = (unsigned short*)(ws + 13008896);      // 37.75 MB
    const size_t WS_NEED = 50757632;

    pool_kernel<<<(B_ * CIN_) / 4, 256, 0, stream>>>(x, pooled);
    se_kernel<<<B_, 256, 0, stream>>>(pooled, fc1_w, fc2_w, fc2_b, prob);

    if (ws_size >= WS_NEED) {
        xpose_kernel<<<B_ * 8 * 25, 256, 0, stream>>>(x, x_t);
        agg_kernel<<<COUT_, 256, 0, stream>>>(weight, prob, agg);
        conv_mfma_kernel<<<7 * 64, 256, 0, stream>>>(x_t, agg, out);
    } else {
        conv_kernel<<<B_ * (COUT_ / 8), 256, 0, stream>>>(x, weight, prob, out);
    }
}

// Round 3
// 156.817 us; speedup vs baseline: 5.3782x; 1.0806x over previous
//
#include <hip/hip_runtime.h>
#include <math.h>

#define B_    32
#define CIN_  256
#define HW_   784
#define H_    28
#define W_    28
#define COUT_ 256
#define KEXP_ 4
#define HID_  64

typedef short short8 __attribute__((ext_vector_type(8)));
typedef float floatx16 __attribute__((ext_vector_type(16)));

__device__ __forceinline__ unsigned short f2bf(float f) {
    union { float f; unsigned int u; } v; v.f = f;
    unsigned int r = (v.u + 0x7FFFu + ((v.u >> 16) & 1u)) >> 16;
    return (unsigned short)r;
}

// ---------------- Kernel 1: fused transpose + partial pool ----------------
// x [b][ic][px] f32 -> x_t [b][px][ic] bf16 ; pooled[b][ic] += sum/784 (atomic)
__global__ __launch_bounds__(256) void xpose_pool_kernel(const float* __restrict__ x,
                                                         unsigned short* __restrict__ x_t,
                                                         float* __restrict__ pooled) {
    __shared__ float tile[32][33];
    int bid = blockIdx.x;              // 32 * 8 * 25
    int b   = bid / 200;
    int rem = bid - b * 200;
    int ic0 = (rem / 25) * 32;
    int px0 = (rem % 25) * 32;
    int t = threadIdx.x;
    int c = t & 31, rr = t >> 5;
    #pragma unroll
    for (int r = 0; r < 4; ++r) {
        int icr = rr + r * 8;
        int px = px0 + c;
        float v = (px < HW_) ? x[((size_t)(b * CIN_ + ic0 + icr)) * HW_ + px] : 0.f;
        tile[icr][c] = v;
    }
    __syncthreads();
    #pragma unroll
    for (int r = 0; r < 4; ++r) {
        int pxr = rr + r * 8;
        int px = px0 + pxr;
        if (px < HW_)
            x_t[((size_t)b * HW_ + px) * CIN_ + ic0 + c] = f2bf(tile[c][pxr]);
    }
    if (t < 32) {
        float s = 0.f;
        #pragma unroll
        for (int cc = 0; cc < 32; ++cc) s += tile[t][cc];
        atomicAdd(&pooled[b * CIN_ + ic0 + t], s * (1.0f / HW_));
    }
}

// ---------------- standalone pool (fallback path only) ----------------
__global__ __launch_bounds__(256) void pool_kernel(const float* __restrict__ x,
                                                   float* __restrict__ pooled) {
    int w = blockIdx.x * 4 + (threadIdx.x >> 6);
    int lane = threadIdx.x & 63;
    const float* p = x + (size_t)w * HW_;
    float s = 0.f;
    for (int i = lane; i < HW_; i += 64) s += p[i];
    for (int off = 32; off; off >>= 1) s += __shfl_down(s, off);
    if (lane == 0) pooled[w] = s * (1.0f / HW_);
}

// ---------------- Kernel 2: SE MLP + softmax, LDS-staged weights ----------------
__global__ __launch_bounds__(256) void se2_kernel(const float* __restrict__ pooled,
                                                  const float* __restrict__ fc1_w,
                                                  const float* __restrict__ fc2_w,
                                                  const float* __restrict__ fc2_b,
                                                  float* __restrict__ prob) {
    __shared__ float pl[CIN_];
    __shared__ float h[HID_];
    __shared__ float wb[16640];   // max(64*257, 256*65)
    int b = blockIdx.x, t = threadIdx.x;
    pl[t] = pooled[b * CIN_ + t];
    // stage fc1_w [64][256] -> wb[r*257 + c], coalesced float4
    #pragma unroll
    for (int i = 0; i < 16; ++i) {
        int l = t + i * 256;                 // float4 index
        float4 v = *(const float4*)(fc1_w + (size_t)l * 4);
        int r = l >> 6, cc = (l & 63) * 4;
        float* dst = &wb[r * 257 + cc];
        dst[0] = v.x; dst[1] = v.y; dst[2] = v.z; dst[3] = v.w;
    }
    __syncthreads();
    if (t < HID_) {
        float s = 0.f;
        const float* wr = &wb[t * 257];
        for (int c = 0; c < CIN_; ++c) s += pl[c] * wr[c];
        h[t] = fmaxf(s, 0.f);
    }
    float yk[KEXP_];
    for (int k = 0; k < KEXP_; ++k) {
        __syncthreads();   // h ready (k=0) / prev-k wb reads done
        #pragma unroll
        for (int i = 0; i < 16; ++i) {
            int l = t + i * 256;
            float4 v = *(const float4*)(fc2_w + (size_t)k * COUT_ * HID_ + (size_t)l * 4);
            int o = l >> 4, jj = (l & 15) * 4;
            float* dst = &wb[o * 65 + jj];
            dst[0] = v.x; dst[1] = v.y; dst[2] = v.z; dst[3] = v.w;
        }
        __syncthreads();
        float s = fc2_b[k * COUT_ + t];
        const float* wr = &wb[t * 65];
        #pragma unroll
        for (int j = 0; j < HID_; ++j) s += h[j] * wr[j];
        yk[k] = s * 0.125f;
    }
    float m = yk[0];
    for (int k = 1; k < KEXP_; ++k) m = fmaxf(m, yk[k]);
    float e[KEXP_], sum = 0.f;
    for (int k = 0; k < KEXP_; ++k) { e[k] = expf(yk[k] - m); sum += e[k]; }
    float inv = 1.0f / sum;
    for (int k = 0; k < KEXP_; ++k)
        prob[b * (KEXP_ * COUT_) + k * COUT_ + t] = e[k] * inv;
}

// ---------------- Kernel 3: aggregate expert weights -> agg[b][rs][oc][ic] bf16 ----------------
// grid = 4 * COUT; bid = grp*COUT + oc (same-oc blocks 256 apart -> same XCD slot)
__global__ __launch_bounds__(256) void agg2_kernel(const float* __restrict__ weight,
                                                   const float* __restrict__ prob,
                                                   unsigned short* __restrict__ agg) {
    __shared__ float ws_w[KEXP_ * CIN_ * 9];   // 36.9 KB
    __shared__ float pb[KEXP_][8];
    int bid = blockIdx.x;
    int oc = bid & 255;
    int b0 = (bid >> 8) * 8;
    int t = threadIdx.x;
    for (int e = t; e < KEXP_ * CIN_ * 9; e += 256) {
        int k = e / (CIN_ * 9);
        int r = e - k * (CIN_ * 9);
        ws_w[e] = weight[((size_t)(k * COUT_ + oc)) * (CIN_ * 9) + r];
    }
    if (t < KEXP_ * 8) {
        int k = t >> 3, bb = t & 7;
        pb[k][bb] = prob[(b0 + bb) * (KEXP_ * COUT_) + k * COUT_ + oc];
    }
    __syncthreads();
    int ic = t;
    for (int rs = 0; rs < 9; ++rs) {
        float w0 = ws_w[0 * CIN_ * 9 + ic * 9 + rs];
        float w1 = ws_w[1 * CIN_ * 9 + ic * 9 + rs];
        float w2 = ws_w[2 * CIN_ * 9 + ic * 9 + rs];
        float w3 = ws_w[3 * CIN_ * 9 + ic * 9 + rs];
        #pragma unroll
        for (int bb = 0; bb < 8; ++bb) {
            float s = pb[0][bb] * w0 + pb[1][bb] * w1 + pb[2][bb] * w2 + pb[3][bb] * w3;
            agg[(((size_t)(b0 + bb) * 9 + rs) * COUT_ + oc) * CIN_ + ic] = f2bf(s);
        }
    }
}

// ---------------- Kernel 4: MFMA implicit-GEMM conv, As double-buffered ----------------
// grid = 7 rowblk * 64 (b*2+ochalf); block 256 threads = 4 waves
__global__ __launch_bounds__(256, 2) void conv_mfma2_kernel(const unsigned short* __restrict__ x_t,
                                                            const unsigned short* __restrict__ agg,
                                                            float* __restrict__ out) {
    __shared__ __align__(16) short Xs[6 * 35 * 72];     // 30240 B
    __shared__ __align__(16) short As[2][128 * 72];     // 36864 B

    int gid = blockIdx.x;
    int rowblk = gid >> 6;
    int pair = gid & 63;
    int b = pair >> 1;
    int oc0 = (pair & 1) * 128;
    int py0 = rowblk * 4;

    int t = threadIdx.x;
    int lane = t & 63, w = t >> 6;
    int ml = lane & 31, kh = lane >> 5;

    floatx16 acc[4];
    #pragma unroll
    for (int j = 0; j < 4; ++j)
        #pragma unroll
        for (int r = 0; r < 16; ++r) acc[j][r] = 0.f;

    const unsigned short* xtb = x_t + (size_t)b * HW_ * CIN_;
    const unsigned short* agb = agg + ((size_t)b * 9 * COUT_ + oc0) * CIN_;

    // A-loader geometry: thread t loads rows t>>3 + {0,32,64,96}, group g = t&7
    int arow = t >> 3, ag = t & 7;

    for (int ic0 = 0; ic0 < CIN_; ic0 += 64) {
        // ---- stage Xs: rows py0-1..py0+4, cols -1..33, 64 ic ----
        #pragma unroll
        for (int i = 0; i < 7; ++i) {
            int l = t + i * 256;
            if (l < 6 * 35 * 8) {
                int pos = l >> 3, g = l & 7;
                int row = pos / 35, col = pos - row * 35;
                int gy = py0 - 1 + row, gx = col - 1;
                short8 v = (short8)0;
                if ((unsigned)gy < 28u && (unsigned)gx < 28u)
                    v = *(const short8*)(xtb + ((size_t)(gy * W_ + gx)) * CIN_ + ic0 + g * 8);
                *(short8*)&Xs[pos * 72 + g * 8] = v;
            }
        }
        // ---- stage As tap 0 into buffer 0 ----
        {
            const unsigned short* ap = agb + ic0 + (size_t)ag * 8;
            #pragma unroll
            for (int i = 0; i < 4; ++i) {
                short8 v = *(const short8*)(ap + (size_t)(arow + i * 32) * CIN_);
                *(short8*)&As[0][(arow + i * 32) * 72 + ag * 8] = v;
            }
        }
        __syncthreads();

        for (int rs = 0; rs < 9; ++rs) {
            int cur = rs & 1;
            int dy = rs / 3, dx = rs - dy * 3;
            // prefetch next tap's A into registers (overlaps with MFMAs below)
            short8 rv0, rv1, rv2, rv3;
            if (rs < 8) {
                const unsigned short* ap = agb + (size_t)(rs + 1) * COUT_ * CIN_ + ic0 + (size_t)ag * 8;
                rv0 = *(const short8*)(ap + (size_t)(arow +  0) * CIN_);
                rv1 = *(const short8*)(ap + (size_t)(arow + 32) * CIN_);
                rv2 = *(const short8*)(ap + (size_t)(arow + 64) * CIN_);
                rv3 = *(const short8*)(ap + (size_t)(arow + 96) * CIN_);
            }
            // ---- MFMA: 4 ksteps x 4 n-tiles ----
            #pragma unroll
            for (int kk = 0; kk < 4; ++kk) {
                short8 a = *(const short8*)&As[cur][(w * 32 + ml) * 72 + kk * 16 + kh * 8];
                #pragma unroll
                for (int j = 0; j < 4; ++j) {
                    short8 bf = *(const short8*)&Xs[((j + dy) * 35 + (ml + dx)) * 72 + kk * 16 + kh * 8];
                    acc[j] = __builtin_amdgcn_mfma_f32_32x32x16_bf16(a, bf, acc[j], 0, 0, 0);
                }
            }
            if (rs < 8) {
                short* dst = &As[cur ^ 1][arow * 72 + ag * 8];
                *(short8*)(dst +  0 * 72)      = rv0;
                *(short8*)(dst + 32 * 72)      = rv1;
                *(short8*)(dst + 64 * 72)      = rv2;
                *(short8*)(dst + 96 * 72)      = rv3;
            }
            __syncthreads();
        }
    }

    // ---- epilogue: D layout col=lane&31, row=(reg&3)+8*(reg>>2)+4*(lane>>5) ----
    int col = ml;
    if (col < W_) {
        #pragma unroll
        for (int j = 0; j < 4; ++j) {
            int y = py0 + j;
            #pragma unroll
            for (int r = 0; r < 16; ++r) {
                int ocg = oc0 + w * 32 + (r & 3) + 8 * (r >> 2) + 4 * kh;
                out[((size_t)(b * COUT_ + ocg)) * HW_ + y * W_ + col] = acc[j][r];
            }
        }
    }
}

// ---------------- Fallback fp32 direct conv (used if ws too small) ----------------
__global__ __launch_bounds__(256) void conv_kernel(const float* __restrict__ x,
                                                   const float* __restrict__ weight,
                                                   const float* __restrict__ prob,
                                                   float* __restrict__ out) {
    __shared__ float xs[30 * 30];
    __shared__ float wagg[8][32][12];
    __shared__ float pl[KEXP_][8];

    int b  = blockIdx.x >> 5;
    int o0 = (blockIdx.x & 31) * 8;
    int t  = threadIdx.x;

    if (t < 32) {
        int k = t >> 3, oc = t & 7;
        pl[k][oc] = prob[b * (KEXP_ * COUT_) + k * COUT_ + o0 + oc];
    }
    int p0 = t;
    int pr[4], pc[4];
    bool pv[4];
    #pragma unroll
    for (int j = 0; j < 4; ++j) {
        int p = p0 + j * 256;
        pv[j] = p < HW_;
        pr[j] = p / W_;
        pc[j] = p % W_;
    }
    float acc[8][4];
    #pragma unroll
    for (int oc = 0; oc < 8; ++oc)
        #pragma unroll
        for (int j = 0; j < 4; ++j) acc[oc][j] = 0.f;

    int aoc = t >> 5, aii = t & 31;

    for (int ic0 = 0; ic0 < CIN_; ic0 += 32) {
        __syncthreads();
        {
            float w9[9];
            #pragma unroll
            for (int j = 0; j < 9; ++j) w9[j] = 0.f;
            int i = ic0 + aii;
            #pragma unroll
            for (int k = 0; k < KEXP_; ++k) {
                float pk = pl[k][aoc];
                const float* wp = weight + ((size_t)(k * COUT_ + o0 + aoc) * CIN_ + i) * 9;
                #pragma unroll
                for (int j = 0; j < 9; ++j) w9[j] += pk * wp[j];
            }
            #pragma unroll
            for (int j = 0; j < 9; ++j) wagg[aoc][aii][j] = w9[j];
        }
        for (int ii = 0; ii < 32; ++ii) {
            int i = ic0 + ii;
            __syncthreads();
            const float* xp = x + (size_t)(b * CIN_ + i) * HW_;
            for (int e = t; e < 900; e += 256) {
                int ry = e / 30, cx = e - ry * 30;
                int gy = ry - 1, gx = cx - 1;
                float v = 0.f;
                if ((unsigned)gy < 28u && (unsigned)gx < 28u) v = xp[gy * W_ + gx];
                xs[e] = v;
            }
            __syncthreads();
            float xv[4][9];
            #pragma unroll
            for (int j = 0; j < 4; ++j) {
                if (pv[j]) {
                    const float* xr = &xs[pr[j] * 30 + pc[j]];
                    xv[j][0] = xr[0];  xv[j][1] = xr[1];  xv[j][2] = xr[2];
                    xv[j][3] = xr[30]; xv[j][4] = xr[31]; xv[j][5] = xr[32];
                    xv[j][6] = xr[60]; xv[j][7] = xr[61]; xv[j][8] = xr[62];
                } else {
                    #pragma unroll
                    for (int q = 0; q < 9; ++q) xv[j][q] = 0.f;
                }
            }
            #pragma unroll
            for (int oc = 0; oc < 8; ++oc) {
                float4 wa = *(const float4*)&wagg[oc][ii][0];
                float4 wb2 = *(const float4*)&wagg[oc][ii][4];
                float  wc = wagg[oc][ii][8];
                #pragma unroll
                for (int j = 0; j < 4; ++j) {
                    acc[oc][j] += xv[j][0] * wa.x + xv[j][1] * wa.y + xv[j][2] * wa.z
                                + xv[j][3] * wa.w + xv[j][4] * wb2.x + xv[j][5] * wb2.y
                                + xv[j][6] * wb2.z + xv[j][7] * wb2.w + xv[j][8] * wc;
                }
            }
        }
    }
    #pragma unroll
    for (int oc = 0; oc < 8; ++oc) {
        float* op = out + (size_t)(b * COUT_ + o0 + oc) * HW_ + p0;
        #pragma unroll
        for (int j = 0; j < 4; ++j)
            if (pv[j]) op[j * 256] = acc[oc][j];
    }
}

extern "C" void kernel_launch(void* const* d_in, const int* in_sizes, int n_in,
                              void* d_out, int out_size, void* d_ws, size_t ws_size,
                              hipStream_t stream) {
    const float* x     = (const float*)d_in[0];
    const float* fc1_w = (const float*)d_in[1];
    const float* fc2_w = (const float*)d_in[2];
    const float* fc2_b = (const float*)d_in[3];
    const float* weight= (const float*)d_in[4];
    float* out = (float*)d_out;

    char* ws = (char*)d_ws;
    float* pooled = (float*)(ws);                    //  32 KB
    float* prob   = (float*)(ws + 32768);            // 128 KB
    unsigned short* x_t = (unsigned short*)(ws + 163840);        // 12.85 MB
    unsigned short* agg = (unsigned short*)(ws + 13008896);      // 37.75 MB
    const size_t WS_NEED = 50757632;

    if (ws_size >= WS_NEED) {
        hipMemsetAsync(pooled, 0, B_ * CIN_ * sizeof(float), stream);
        xpose_pool_kernel<<<B_ * 8 * 25, 256, 0, stream>>>(x, x_t, pooled);
        se2_kernel<<<B_, 256, 0, stream>>>(pooled, fc1_w, fc2_w, fc2_b, prob);
        agg2_kernel<<<4 * COUT_, 256, 0, stream>>>(weight, prob, agg);
        conv_mfma2_kernel<<<7 * 64, 256, 0, stream>>>(x_t, agg, out);
    } else {
        pool_kernel<<<(B_ * CIN_) / 4, 256, 0, stream>>>(x, pooled);
        se2_kernel<<<B_, 256, 0, stream>>>(pooled, fc1_w, fc2_w, fc2_b, prob);
        conv_kernel<<<B_ * (COUT_ / 8), 256, 0, stream>>>(x, weight, prob, out);
    }
}

// Round 4
// 149.892 us; speedup vs baseline: 5.6267x; 1.0462x over previous
//
#include <hip/hip_runtime.h>
#include <math.h>

#define B_    32
#define CIN_  256
#define HW_   784
#define H_    28
#define W_    28
#define COUT_ 256
#define KEXP_ 4
#define HID_  64

typedef short short8 __attribute__((ext_vector_type(8)));
typedef unsigned short ushort4v __attribute__((ext_vector_type(4)));
typedef float floatx16 __attribute__((ext_vector_type(16)));

__device__ __forceinline__ unsigned short f2bf(float f) {
    union { float f; unsigned int u; } v; v.f = f;
    unsigned int r = (v.u + 0x7FFFu + ((v.u >> 16) & 1u)) >> 16;
    return (unsigned short)r;
}

// ---------------- Kernel 1: transpose + partial pool (no atomics) ----------------
// x [b][ic][px] f32 -> x_t [b][px][ic] bf16 ; partial[(b*25+pxt)*256 + ic] = rowsum/784
__global__ __launch_bounds__(256) void xpose_pool_kernel(const float* __restrict__ x,
                                                         unsigned short* __restrict__ x_t,
                                                         float* __restrict__ partial) {
    __shared__ float tile[32][33];
    int bid = blockIdx.x;              // 32 * 8 * 25
    int b   = bid / 200;
    int rem = bid - b * 200;
    int icg = rem / 25;
    int pxt = rem % 25;
    int ic0 = icg * 32;
    int px0 = pxt * 32;
    int t = threadIdx.x;
    int c = t & 31, rr = t >> 5;
    #pragma unroll
    for (int r = 0; r < 4; ++r) {
        int icr = rr + r * 8;
        int px = px0 + c;
        float v = (px < HW_) ? x[((size_t)(b * CIN_ + ic0 + icr)) * HW_ + px] : 0.f;
        tile[icr][c] = v;
    }
    __syncthreads();
    #pragma unroll
    for (int r = 0; r < 4; ++r) {
        int pxr = rr + r * 8;
        int px = px0 + pxr;
        if (px < HW_)
            x_t[((size_t)b * HW_ + px) * CIN_ + ic0 + c] = f2bf(tile[c][pxr]);
    }
    if (t < 32) {
        float s = 0.f;
        #pragma unroll
        for (int cc = 0; cc < 32; ++cc) s += tile[t][cc];
        partial[((size_t)b * 25 + pxt) * CIN_ + ic0 + t] = s * (1.0f / HW_);
    }
}

// ---------------- standalone pool (fallback path only) ----------------
__global__ __launch_bounds__(256) void pool_kernel(const float* __restrict__ x,
                                                   float* __restrict__ pooled) {
    int w = blockIdx.x * 4 + (threadIdx.x >> 6);
    int lane = threadIdx.x & 63;
    const float* p = x + (size_t)w * HW_;
    float s = 0.f;
    for (int i = lane; i < HW_; i += 64) s += p[i];
    for (int off = 32; off; off >>= 1) s += __shfl_down(s, off);
    if (lane == 0) pooled[w] = s * (1.0f / HW_);
}

// ---------------- Kernel 2: SE MLP + softmax (reads partial pools) ----------------
__global__ __launch_bounds__(256) void se3_kernel(const float* __restrict__ partial,
                                                  const float* __restrict__ fc1_w,
                                                  const float* __restrict__ fc2_w,
                                                  const float* __restrict__ fc2_b,
                                                  float* __restrict__ prob) {
    __shared__ float pl[CIN_];
    __shared__ float h[HID_];
    __shared__ float wb[16640];
    int b = blockIdx.x, t = threadIdx.x;
    {
        float s = 0.f;
        for (int pt = 0; pt < 25; ++pt)
            s += partial[((size_t)b * 25 + pt) * CIN_ + t];
        pl[t] = s;
    }
    #pragma unroll
    for (int i = 0; i < 16; ++i) {
        int l = t + i * 256;
        float4 v = *(const float4*)(fc1_w + (size_t)l * 4);
        int r = l >> 6, cc = (l & 63) * 4;
        float* dst = &wb[r * 257 + cc];
        dst[0] = v.x; dst[1] = v.y; dst[2] = v.z; dst[3] = v.w;
    }
    __syncthreads();
    if (t < HID_) {
        float s = 0.f;
        const float* wr = &wb[t * 257];
        for (int c = 0; c < CIN_; ++c) s += pl[c] * wr[c];
        h[t] = fmaxf(s, 0.f);
    }
    float yk[KEXP_];
    for (int k = 0; k < KEXP_; ++k) {
        __syncthreads();
        #pragma unroll
        for (int i = 0; i < 16; ++i) {
            int l = t + i * 256;
            float4 v = *(const float4*)(fc2_w + (size_t)k * COUT_ * HID_ + (size_t)l * 4);
            int o = l >> 4, jj = (l & 15) * 4;
            float* dst = &wb[o * 65 + jj];
            dst[0] = v.x; dst[1] = v.y; dst[2] = v.z; dst[3] = v.w;
        }
        __syncthreads();
        float s = fc2_b[k * COUT_ + t];
        const float* wr = &wb[t * 65];
        #pragma unroll
        for (int j = 0; j < HID_; ++j) s += h[j] * wr[j];
        yk[k] = s * 0.125f;
    }
    float m = yk[0];
    for (int k = 1; k < KEXP_; ++k) m = fmaxf(m, yk[k]);
    float e[KEXP_], sum = 0.f;
    for (int k = 0; k < KEXP_; ++k) { e[k] = expf(yk[k] - m); sum += e[k]; }
    float inv = 1.0f / sum;
    for (int k = 0; k < KEXP_; ++k)
        prob[b * (KEXP_ * COUT_) + k * COUT_ + t] = e[k] * inv;
}

// ---------------- SE from pooled (fallback path only) ----------------
__global__ __launch_bounds__(256) void se2_kernel(const float* __restrict__ pooled,
                                                  const float* __restrict__ fc1_w,
                                                  const float* __restrict__ fc2_w,
                                                  const float* __restrict__ fc2_b,
                                                  float* __restrict__ prob) {
    __shared__ float pl[CIN_];
    __shared__ float h[HID_];
    __shared__ float wb[16640];
    int b = blockIdx.x, t = threadIdx.x;
    pl[t] = pooled[b * CIN_ + t];
    #pragma unroll
    for (int i = 0; i < 16; ++i) {
        int l = t + i * 256;
        float4 v = *(const float4*)(fc1_w + (size_t)l * 4);
        int r = l >> 6, cc = (l & 63) * 4;
        float* dst = &wb[r * 257 + cc];
        dst[0] = v.x; dst[1] = v.y; dst[2] = v.z; dst[3] = v.w;
    }
    __syncthreads();
    if (t < HID_) {
        float s = 0.f;
        const float* wr = &wb[t * 257];
        for (int c = 0; c < CIN_; ++c) s += pl[c] * wr[c];
        h[t] = fmaxf(s, 0.f);
    }
    float yk[KEXP_];
    for (int k = 0; k < KEXP_; ++k) {
        __syncthreads();
        #pragma unroll
        for (int i = 0; i < 16; ++i) {
            int l = t + i * 256;
            float4 v = *(const float4*)(fc2_w + (size_t)k * COUT_ * HID_ + (size_t)l * 4);
            int o = l >> 4, jj = (l & 15) * 4;
            float* dst = &wb[o * 65 + jj];
            dst[0] = v.x; dst[1] = v.y; dst[2] = v.z; dst[3] = v.w;
        }
        __syncthreads();
        float s = fc2_b[k * COUT_ + t];
        const float* wr = &wb[t * 65];
        #pragma unroll
        for (int j = 0; j < HID_; ++j) s += h[j] * wr[j];
        yk[k] = s * 0.125f;
    }
    float m = yk[0];
    for (int k = 1; k < KEXP_; ++k) m = fmaxf(m, yk[k]);
    float e[KEXP_], sum = 0.f;
    for (int k = 0; k < KEXP_; ++k) { e[k] = expf(yk[k] - m); sum += e[k]; }
    float inv = 1.0f / sum;
    for (int k = 0; k < KEXP_; ++k)
        prob[b * (KEXP_ * COUT_) + k * COUT_ + t] = e[k] * inv;
}

// ---------------- Kernel 3: aggregate expert weights -> agg[b][rs][oc][ic] bf16 ----------------
// grid = 4*COUT; bid: oc = bid&255, b0 = (bid>>8)*8
__global__ __launch_bounds__(256) void agg3_kernel(const float* __restrict__ weight,
                                                   const float* __restrict__ prob,
                                                   unsigned short* __restrict__ agg) {
    __shared__ float ws_w[KEXP_ * CIN_ * 9];   // [k][ic*9+rs], 36.9 KB
    __shared__ float pb[KEXP_][8];
    int bid = blockIdx.x;
    int oc = bid & 255;
    int b0 = (bid >> 8) * 8;
    int t = threadIdx.x;
    #pragma unroll
    for (int i = 0; i < 9; ++i) {
        int e4 = t + i * 256;                  // < 2304 float4s
        int k = e4 / 576;
        int r4 = e4 - k * 576;
        float4 v = *(const float4*)(weight + (size_t)k * 589824 + (size_t)oc * 2304 + (size_t)r4 * 4);
        *(float4*)&ws_w[e4 * 4] = v;
    }
    if (t < KEXP_ * 8) {
        int k = t >> 3, bb = t & 7;
        pb[k][bb] = prob[(size_t)(b0 + bb) * (KEXP_ * COUT_) + k * COUT_ + oc];
    }
    __syncthreads();
    int icg = t & 63, blane = t >> 6;
    for (int rs = 0; rs < 9; ++rs) {
        float wv[4][4];
        #pragma unroll
        for (int q = 0; q < 4; ++q)
            #pragma unroll
            for (int k = 0; k < 4; ++k)
                wv[q][k] = ws_w[k * 2304 + (icg * 4 + q) * 9 + rs];
        #pragma unroll
        for (int bb = 0; bb < 2; ++bb) {
            int bidx = blane * 2 + bb;
            float p0 = pb[0][bidx], p1 = pb[1][bidx], p2 = pb[2][bidx], p3 = pb[3][bidx];
            ushort4v pack;
            #pragma unroll
            for (int q = 0; q < 4; ++q) {
                float s = p0 * wv[q][0] + p1 * wv[q][1] + p2 * wv[q][2] + p3 * wv[q][3];
                pack[q] = f2bf(s);
            }
            *(ushort4v*)(agg + ((((size_t)(b0 + bidx) * 9 + rs) * COUT_ + oc)) * CIN_ + icg * 4) = pack;
        }
    }
}

// ---------------- Kernel 4: MFMA implicit-GEMM conv, A from global, dy-reuse ----------------
// grid = 256: b = gid&31, half = (gid>>5)&1, rowblk = gid>>6 (7 rows each)
__global__ __launch_bounds__(256, 1) void conv_mfma3_kernel(const unsigned short* __restrict__ x_t,
                                                            const unsigned short* __restrict__ agg,
                                                            float* __restrict__ out) {
    __shared__ __align__(16) short Xs[2][9 * 35 * 72];   // 2 x 45360 B = 90720 B

    int gid = blockIdx.x;
    int b      = gid & 31;
    int oc0    = ((gid >> 5) & 1) * 128;
    int rowblk = gid >> 6;
    int py0 = rowblk * 7;

    int t = threadIdx.x;
    int lane = t & 63, w = t >> 6;
    int ml = lane & 31, kh = lane >> 5;

    floatx16 acc[7];
    #pragma unroll
    for (int j = 0; j < 7; ++j)
        #pragma unroll
        for (int r = 0; r < 16; ++r) acc[j][r] = 0.f;

    const unsigned short* xtb = x_t + (size_t)b * HW_ * CIN_;
    // per-lane A pointer: agg[b][rs=0][oc0 + w*32 + ml][kh*8]
    const unsigned short* aln = agg + (((size_t)b * 9 * COUT_) + oc0 + w * 32 + ml) * CIN_ + kh * 8;

    // ---- stage chunk 0 into buf 0 ----
    {
        #pragma unroll
        for (int i = 0; i < 10; ++i) {
            int l = t + i * 256;
            if (l < 2520) {
                int pos = l >> 3, g = l & 7;
                int row = pos / 35, col = pos - row * 35;
                int gy = py0 - 1 + row, gx = col - 1;
                short8 v = (short8)0;
                if ((unsigned)gy < 28u && (unsigned)gx < 28u)
                    v = *(const short8*)(xtb + ((size_t)(gy * W_ + gx)) * CIN_ + g * 8);
                *(short8*)&Xs[0][pos * 72 + g * 8] = v;
            }
        }
    }

    // ---- prologue: A for pair (ic=0, kk=0, dx=0) ----
    short8 Acur0, Acur1, Acur2, Anext0, Anext1, Anext2;
    Acur0 = *(const short8*)(aln + (size_t)(0 * 3 + 0) * (COUT_ * CIN_));
    Acur1 = *(const short8*)(aln + (size_t)(1 * 3 + 0) * (COUT_ * CIN_));
    Acur2 = *(const short8*)(aln + (size_t)(2 * 3 + 0) * (COUT_ * CIN_));
    // rolling "next pair" state
    int dxn = 1, kkn = 0, icn = 0;

    __syncthreads();

    for (int c = 0; c < 4; ++c) {
        int ic0 = c * 64;
        const short* xb = &Xs[c & 1][0];

        // issue staging loads for next chunk (held in regs, written after compute)
        short8 Xl[10];
        if (c < 3) {
            #pragma unroll
            for (int i = 0; i < 10; ++i) {
                int l = t + i * 256;
                short8 v = (short8)0;
                if (l < 2520) {
                    int pos = l >> 3, g = l & 7;
                    int row = pos / 35, col = pos - row * 35;
                    int gy = py0 - 1 + row, gx = col - 1;
                    if ((unsigned)gy < 28u && (unsigned)gx < 28u)
                        v = *(const short8*)(xtb + ((size_t)(gy * W_ + gx)) * CIN_ + ic0 + 64 + g * 8);
                }
                Xl[i] = v;
            }
        }

        for (int kk = 0; kk < 4; ++kk) {
            for (int dx = 0; dx < 3; ++dx) {
                // prefetch A for next pair
                if (icn < 256) {
                    const unsigned short* ap = aln + icn + kkn * 16;
                    Anext0 = *(const short8*)(ap + (size_t)(0 * 3 + dxn) * (COUT_ * CIN_));
                    Anext1 = *(const short8*)(ap + (size_t)(1 * 3 + dxn) * (COUT_ * CIN_));
                    Anext2 = *(const short8*)(ap + (size_t)(2 * 3 + dxn) * (COUT_ * CIN_));
                    ++dxn;
                    if (dxn == 3) { dxn = 0; ++kkn; if (kkn == 4) { kkn = 0; icn += 64; } }
                }
                // compute: 9 Xs rows, B reused across 3 dy taps
                int va = (ml + dx) * 72 + kk * 16 + kh * 8;
                #pragma unroll
                for (int r = 0; r < 9; ++r) {
                    short8 Bf = *(const short8*)&xb[r * 2520 + va];
                    if (r <= 6)
                        acc[r]     = __builtin_amdgcn_mfma_f32_32x32x16_bf16(Acur0, Bf, acc[r], 0, 0, 0);
                    if (r >= 1 && r - 1 <= 6)
                        acc[r - 1] = __builtin_amdgcn_mfma_f32_32x32x16_bf16(Acur1, Bf, acc[r - 1], 0, 0, 0);
                    if (r >= 2)
                        acc[r - 2] = __builtin_amdgcn_mfma_f32_32x32x16_bf16(Acur2, Bf, acc[r - 2], 0, 0, 0);
                }
                Acur0 = Anext0; Acur1 = Anext1; Acur2 = Anext2;
            }
        }

        if (c < 3) {
            short* dstb = &Xs[(c & 1) ^ 1][0];
            #pragma unroll
            for (int i = 0; i < 10; ++i) {
                int l = t + i * 256;
                if (l < 2520) {
                    int pos = l >> 3, g = l & 7;
                    *(short8*)&dstb[pos * 72 + g * 8] = Xl[i];
                }
            }
        }
        __syncthreads();
    }

    // ---- epilogue: D layout col=lane&31, row=(reg&3)+8*(reg>>2)+4*(lane>>5) ----
    if (ml < W_) {
        #pragma unroll
        for (int j = 0; j < 7; ++j) {
            float* op = out + ((size_t)(b * COUT_ + oc0 + w * 32)) * HW_ + (py0 + j) * W_ + ml;
            #pragma unroll
            for (int r = 0; r < 16; ++r) {
                int ocd = (r & 3) + 8 * (r >> 2) + 4 * kh;
                op[(size_t)ocd * HW_] = acc[j][r];
            }
        }
    }
}

// ---------------- Fallback fp32 direct conv ----------------
__global__ __launch_bounds__(256) void conv_kernel(const float* __restrict__ x,
                                                   const float* __restrict__ weight,
                                                   const float* __restrict__ prob,
                                                   float* __restrict__ out) {
    __shared__ float xs[30 * 30];
    __shared__ float wagg[8][32][12];
    __shared__ float pl[KEXP_][8];

    int b  = blockIdx.x >> 5;
    int o0 = (blockIdx.x & 31) * 8;
    int t  = threadIdx.x;

    if (t < 32) {
        int k = t >> 3, oc = t & 7;
        pl[k][oc] = prob[b * (KEXP_ * COUT_) + k * COUT_ + o0 + oc];
    }
    int p0 = t;
    int pr[4], pc[4];
    bool pv[4];
    #pragma unroll
    for (int j = 0; j < 4; ++j) {
        int p = p0 + j * 256;
        pv[j] = p < HW_;
        pr[j] = p / W_;
        pc[j] = p % W_;
    }
    float acc[8][4];
    #pragma unroll
    for (int oc = 0; oc < 8; ++oc)
        #pragma unroll
        for (int j = 0; j < 4; ++j) acc[oc][j] = 0.f;

    int aoc = t >> 5, aii = t & 31;

    for (int ic0 = 0; ic0 < CIN_; ic0 += 32) {
        __syncthreads();
        {
            float w9[9];
            #pragma unroll
            for (int j = 0; j < 9; ++j) w9[j] = 0.f;
            int i = ic0 + aii;
            #pragma unroll
            for (int k = 0; k < KEXP_; ++k) {
                float pk = pl[k][aoc];
                const float* wp = weight + ((size_t)(k * COUT_ + o0 + aoc) * CIN_ + i) * 9;
                #pragma unroll
                for (int j = 0; j < 9; ++j) w9[j] += pk * wp[j];
            }
            #pragma unroll
            for (int j = 0; j < 9; ++j) wagg[aoc][aii][j] = w9[j];
        }
        for (int ii = 0; ii < 32; ++ii) {
            int i = ic0 + ii;
            __syncthreads();
            const float* xp = x + (size_t)(b * CIN_ + i) * HW_;
            for (int e = t; e < 900; e += 256) {
                int ry = e / 30, cx = e - ry * 30;
                int gy = ry - 1, gx = cx - 1;
                float v = 0.f;
                if ((unsigned)gy < 28u && (unsigned)gx < 28u) v = xp[gy * W_ + gx];
                xs[e] = v;
            }
            __syncthreads();
            float xv[4][9];
            #pragma unroll
            for (int j = 0; j < 4; ++j) {
                if (pv[j]) {
                    const float* xr = &xs[pr[j] * 30 + pc[j]];
                    xv[j][0] = xr[0];  xv[j][1] = xr[1];  xv[j][2] = xr[2];
                    xv[j][3] = xr[30]; xv[j][4] = xr[31]; xv[j][5] = xr[32];
                    xv[j][6] = xr[60]; xv[j][7] = xr[61]; xv[j][8] = xr[62];
                } else {
                    #pragma unroll
                    for (int q = 0; q < 9; ++q) xv[j][q] = 0.f;
                }
            }
            #pragma unroll
            for (int oc = 0; oc < 8; ++oc) {
                float4 wa = *(const float4*)&wagg[oc][ii][0];
                float4 wb2 = *(const float4*)&wagg[oc][ii][4];
                float  wc = wagg[oc][ii][8];
                #pragma unroll
                for (int j = 0; j < 4; ++j) {
                    acc[oc][j] += xv[j][0] * wa.x + xv[j][1] * wa.y + xv[j][2] * wa.z
                                + xv[j][3] * wa.w + xv[j][4] * wb2.x + xv[j][5] * wb2.y
                                + xv[j][6] * wb2.z + xv[j][7] * wb2.w + xv[j][8] * wc;
                }
            }
        }
    }
    #pragma unroll
    for (int oc = 0; oc < 8; ++oc) {
        float* op = out + (size_t)(b * COUT_ + o0 + oc) * HW_ + p0;
        #pragma unroll
        for (int j = 0; j < 4; ++j)
            if (pv[j]) op[j * 256] = acc[oc][j];
    }
}

extern "C" void kernel_launch(void* const* d_in, const int* in_sizes, int n_in,
                              void* d_out, int out_size, void* d_ws, size_t ws_size,
                              hipStream_t stream) {
    const float* x     = (const float*)d_in[0];
    const float* fc1_w = (const float*)d_in[1];
    const float* fc2_w = (const float*)d_in[2];
    const float* fc2_b = (const float*)d_in[3];
    const float* weight= (const float*)d_in[4];
    float* out = (float*)d_out;

    char* ws = (char*)d_ws;
    // layout (main path): prob @0 (128KB), x_t @131072 (12.85MB), agg @12976128 (37.75MB)
    // partial pools overlap the agg region (consumed by se3 before agg3 writes)
    float* prob = (float*)(ws);
    unsigned short* x_t = (unsigned short*)(ws + 131072);
    unsigned short* agg = (unsigned short*)(ws + 12976128);
    float* partial = (float*)(ws + 12976128);          // 32*25*256 floats = 819200 B
    const size_t WS_NEED = 12976128 + (size_t)B_ * 9 * COUT_ * CIN_ * 2;  // 50724864

    if (ws_size >= WS_NEED) {
        xpose_pool_kernel<<<B_ * 8 * 25, 256, 0, stream>>>(x, x_t, partial);
        se3_kernel<<<B_, 256, 0, stream>>>(partial, fc1_w, fc2_w, fc2_b, prob);
        agg3_kernel<<<4 * COUT_, 256, 0, stream>>>(weight, prob, agg);
        conv_mfma3_kernel<<<256, 256, 0, stream>>>(x_t, agg, out);
    } else {
        float* pooled = (float*)(ws + 131072);
        pool_kernel<<<(B_ * CIN_) / 4, 256, 0, stream>>>(x, pooled);
        se2_kernel<<<B_, 256, 0, stream>>>(pooled, fc1_w, fc2_w, fc2_b, prob);
        conv_kernel<<<B_ * (COUT_ / 8), 256, 0, stream>>>(x, weight, prob, out);
    }
}